// Round 3
// baseline (330.666 us; speedup 1.0000x reference)
//
#include <hip/hip_runtime.h>
#include <hip/hip_bf16.h>
#include <math.h>

#define NB 32          // batch
#define TLEN 160000    // samples per batch
#define KFFT 1024      // n_fft
#define MWIN 800       // win_length
#define HOP 600
#define NBINS 256
#define TT 267         // frames: 1 + (160000+1024-1024)/600
#define NTOT (NBINS * TT)   // 68352 candidates per batch
#define LMAX 13
#define LMIN 3

__device__ __forceinline__ unsigned f2key(float f) {
    unsigned b = __float_as_uint(f);
    return (b & 0x80000000u) ? ~b : (b | 0x80000000u);
}

// ---------------------------------------------------------------- twiddles
__global__ void twiddle_init_kernel(float2* __restrict__ tw) {
    int j = blockIdx.x * blockDim.x + threadIdx.x;
    if (j < 512) {
        double ang = -2.0 * 3.14159265358979323846 * (double)j / 1024.0;
        tw[j] = make_float2((float)cos(ang), (float)sin(ang));
    }
}

// ---------------------------------------------------------------- STFT power
// one block per (frame, batch); 256 threads; 1024-pt radix-2 DIT FFT in LDS
__global__ __launch_bounds__(256) void stft_power_kernel(
        const float* __restrict__ y, const float2* __restrict__ twg,
        float* __restrict__ Y) {
    __shared__ float re[1024];
    __shared__ float im[1024];
    __shared__ float twc[512];
    __shared__ float tws[512];

    const int f = blockIdx.x;   // frame
    const int b = blockIdx.y;   // batch
    const int tid = threadIdx.x;

    for (int j = tid; j < 512; j += 256) {
        float2 t = twg[j];
        twc[j] = t.x; tws[j] = t.y;
    }

    const float* yb = y + (size_t)b * TLEN;
    for (int i = tid; i < 1024; i += 256) {
        int n = (int)(__brev((unsigned)i) >> 22);   // 10-bit reverse
        float v = 0.0f;
        if (n >= 112 && n < 912) {                  // centered 800-tap hann
            int pos = f * HOP + n - 512;            // reflect pad K/2 = 512
            if (pos < 0) pos = -pos;
            else if (pos >= TLEN) pos = 2 * TLEN - 2 - pos;
            float nf = (float)(n - 112);
            float arg = (6.2831855f * nf) / 800.0f;
            float w = 0.5f - 0.5f * cosf(arg);
            v = yb[pos] * w;
        }
        re[i] = v;
        im[i] = 0.0f;
    }
    __syncthreads();

    for (int s = 0; s < 10; ++s) {
        const int half = 1 << s;
        for (int k = tid; k < 512; k += 256) {
            int j  = k & (half - 1);
            int i0 = ((k >> s) << (s + 1)) | j;
            int i1 = i0 + half;
            int tj = j << (9 - s);
            float c = twc[tj], sn = tws[tj];
            float ar = re[i0], ai = im[i0];
            float br = re[i1], bi = im[i1];
            float tr = br * c - bi * sn;
            float ti = br * sn + bi * c;
            re[i0] = ar + tr; im[i0] = ai + ti;
            re[i1] = ar - tr; im[i1] = ai - ti;
        }
        __syncthreads();
    }

    float pr = re[tid], pi = im[tid];
    Y[((size_t)b * NBINS + tid) * TT + f] = pr * pr + pi * pi;
}

// ---------------------------------------------------------------- per-subband
// one block per (b,f). dec flags packed via ballot -> runlen = trailing ones
// of a 12-bit window (L is capped at 13, so no scan needed). Valid rt60 keys
// are appended to a per-batch compact buffer.
__global__ __launch_bounds__(256) void subband_kernel(
        const float* __restrict__ Y, unsigned* __restrict__ compact,
        int* __restrict__ cnt) {
    __shared__ float ys[TT];
    __shared__ unsigned long long decw[5];
    __shared__ int wmax[4];
    __shared__ int maxrun_s;

    const int tid = threadIdx.x;
    const int lane = tid & 63;
    const int wave = tid >> 6;
    const int b = blockIdx.x >> 8;          // 256 subbands per batch
    const float* row = Y + (size_t)blockIdx.x * TT;

    for (int t = tid; t < TT; t += 256) ys[t] = row[t];
    __syncthreads();

    // dec[t] = ys[t+1] < ys[t], packed 64/wave via ballot
    for (int c = wave; c < 5; c += 4) {
        int t = c * 64 + lane;
        bool d = (t < TT - 1) && (ys[t + 1] < ys[t]);
        unsigned long long m = __ballot(d);
        if (lane == 0) decw[c] = m;
    }
    __syncthreads();

    // runlen capped at 12 = trailing ones of dec[t..t+11]
    auto runlen = [&](int t) -> int {
        int w = t >> 6, off = t & 63;
        unsigned long long lo = decw[w] >> off;
        if (off && w < 4) lo |= decw[w + 1] << (64 - off);
        unsigned win = (unsigned)lo & 0xFFFu;
        return (win == 0xFFFu) ? 12 : (__ffs(~win) - 1);
    };

    const int rl0 = runlen(tid);
    const int rl1 = (tid + 256 < TT) ? runlen(tid + 256) : 0;

    int m = max(rl0, rl1);
    #pragma unroll
    for (int o = 32; o; o >>= 1) m = max(m, __shfl_xor(m, o));
    if (lane == 0) wmax[wave] = m;
    __syncthreads();
    if (tid == 0)
        maxrun_s = max(max(wmax[0], wmax[1]), max(wmax[2], wmax[3]));
    __syncthreads();

    const int maxrun = maxrun_s;            // capped at 12
    if (maxrun < 2) return;                 // has_any == false
    const int L = maxrun + 1;               // == min(13, true_maxrun+1)

    float sumx = 0.0f;
    #pragma unroll
    for (int j = 0; j < LMAX; ++j) if (j < L) sumx += (float)j;
    const float xm = sumx / (float)L;
    float den = 0.0f;
    #pragma unroll
    for (int j = 0; j < LMAX; ++j) if (j < L) { float xc = (float)j - xm; den += xc * xc; }

    for (int t = tid; t < TT; t += 256) {
        const int rl = (t == tid) ? rl0 : rl1;
        if (rl >= L - 1) {                  // start_mask (t+L<=T implied)
            float edc[LMAX];
            float s = 0.0f;
            #pragma unroll
            for (int j = LMAX - 1; j >= 0; --j) {
                if (j < L) s += ys[t + j];
                edc[j] = s;
            }
            float db0 = 10.0f * log10f(fmaxf(edc[0], 1e-10f));
            float scl[LMAX];
            float s1 = 0.0f;
            float last = 0.0f;
            #pragma unroll
            for (int j = 0; j < LMAX; ++j) {
                if (j < L) {
                    float db = 10.0f * log10f(fmaxf(edc[j], 1e-10f));
                    float sc = db - db0;
                    scl[j] = sc;
                    s1 += sc;
                    if (j == L - 1) last = sc;
                }
            }
            if (last < -10.0f) {            // selected
                const float ym = s1 / (float)L;
                float num = 0.0f;
                #pragma unroll
                for (int j = 0; j < LMAX; ++j)
                    if (j < L) num += ((float)j - xm) * (scl[j] - ym);
                const float slope = num / den;
                float rt60 = (-60.0f / slope) * 0.0375f;   // * HOP/FS
                int idx = atomicAdd(&cnt[b], 1);
                if (idx < NTOT) compact[(size_t)b * NTOT + idx] = f2key(rt60);
            }
        }
    }
}

// ---------------------------------------------------------------- median
// one block per batch: exact k-th smallest of cnt[b] compacted keys via
// 3-pass (14+14+4 bit) LDS-histogram radix select.
__global__ __launch_bounds__(256) void median_kernel(
        const unsigned* __restrict__ compact, const int* __restrict__ cnt,
        const float* __restrict__ coeffs, float* __restrict__ out) {
    __shared__ unsigned hist[16384];
    __shared__ unsigned csum[256];
    __shared__ unsigned sh_kk, sh_prefix, sh_pmask;

    const int b = blockIdx.x;
    const int tid = threadIdx.x;
    const int n = min(cnt[b], NTOT);
    const unsigned* kb = compact + (size_t)b * NTOT;

    if (tid == 0) {
        sh_kk = (n > 0) ? (unsigned)((n - 1) / 2) : 0u;
        sh_prefix = 0u; sh_pmask = 0u;
    }
    __syncthreads();

    const int shifts[3] = {18, 4, 0};
    const int nbins_[3] = {16384, 16384, 16};

    for (int p = 0; p < 3; ++p) {
        const int shift = shifts[p];
        const unsigned nb = (unsigned)nbins_[p];
        const unsigned bmask = nb - 1u;

        for (int i = tid; i < (int)nb; i += 256) hist[i] = 0u;
        __syncthreads();

        const unsigned pfx = sh_prefix, pm = sh_pmask;
        for (int i = tid; i < n; i += 256) {
            unsigned k = kb[i];
            if ((k & pm) == pfx) atomicAdd(&hist[(k >> shift) & bmask], 1u);
        }
        __syncthreads();

        if (nb >= 256u) {
            const int csz = (int)(nb >> 8);
            unsigned s = 0;
            for (int i = 0; i < csz; ++i) s += hist[tid * csz + i];
            csum[tid] = s;
        }
        __syncthreads();

        if (tid == 0) {
            unsigned kk = sh_kk, cum = 0, sel = 0;
            if (nb >= 256u) {
                const int csz = (int)(nb >> 8);
                int c = 255;
                for (int i = 0; i < 256; ++i) {
                    unsigned h = csum[i];
                    if (kk < cum + h) { c = i; break; }
                    cum += h;
                }
                for (int i = 0; i < csz; ++i) {
                    unsigned h = hist[c * csz + i];
                    if (kk < cum + h) { sel = (unsigned)(c * csz + i); break; }
                    cum += h;
                }
            } else {
                for (unsigned i = 0; i < nb; ++i) {
                    unsigned h = hist[i];
                    if (kk < cum + h) { sel = i; break; }
                    cum += h;
                }
            }
            sh_kk = kk - cum;
            sh_prefix = sh_prefix | (sel << shift);
            sh_pmask = sh_pmask | (bmask << shift);
        }
        __syncthreads();
    }

    if (tid == 0) {
        unsigned kx = sh_prefix;
        unsigned fb = (kx & 0x80000000u) ? (kx & 0x7FFFFFFFu) : ~kx;
        float med = __uint_as_float(fb);
        float o = (n > 0) ? (coeffs[0] + coeffs[1] * med) : 0.5f;
        out[b] = fmaxf(o, 0.01f);
    }
}

// ----------------------------------------------------------------
extern "C" void kernel_launch(void* const* d_in, const int* in_sizes, int n_in,
                              void* d_out, int out_size, void* d_ws, size_t ws_size,
                              hipStream_t stream) {
    const float* y = (const float*)d_in[0];
    const float* coeffs = (const float*)d_in[1];
    float* out = (float*)d_out;

    // ws layout:
    //   [0]        Y       : NB*NBINS*TT floats = 8,749,056 B
    //   [YB]       compact : NB*NTOT uints      = 8,749,056 B
    //   [2*YB]     cnt     : NB ints (zeroed per call)
    //   [..+128]   tw      : 512 float2
    const size_t YB = (size_t)NB * NBINS * TT * sizeof(float);
    char* base = (char*)d_ws;
    float* Y = (float*)base;
    unsigned* compact = (unsigned*)(base + YB);
    int* cnt = (int*)(base + 2 * YB);
    float2* tw = (float2*)(base + 2 * YB + 128);

    hipMemsetAsync(cnt, 0, NB * sizeof(int), stream);
    twiddle_init_kernel<<<2, 256, 0, stream>>>(tw);
    stft_power_kernel<<<dim3(TT, NB), 256, 0, stream>>>(y, tw, Y);
    subband_kernel<<<NB * NBINS, 256, 0, stream>>>(Y, compact, cnt);
    median_kernel<<<NB, 256, 0, stream>>>(compact, cnt, coeffs, out);
}

// Round 4
// 235.348 us; speedup vs baseline: 1.4050x; 1.4050x over previous
//
#include <hip/hip_runtime.h>
#include <hip/hip_bf16.h>
#include <math.h>

#define NB 32          // batch
#define TLEN 160000    // samples per batch
#define KFFT 1024      // n_fft
#define MWIN 800       // win_length
#define HOP 600
#define NBINS 256
#define TT 267         // frames: 1 + (160000+1024-1024)/600
#define NTOT (NBINS * TT)   // 68352 candidates per batch
#define LMAX 13
#define LMIN 3

__device__ __forceinline__ unsigned f2key(float f) {
    unsigned b = __float_as_uint(f);
    return (b & 0x80000000u) ? ~b : (b | 0x80000000u);
}

// ---------------------------------------------------------------- twiddles (+cnt zero)
__global__ void twiddle_init_kernel(float2* __restrict__ tw, int* __restrict__ cnt) {
    int j = blockIdx.x * blockDim.x + threadIdx.x;
    if (j < 512) {
        double ang = -2.0 * 3.14159265358979323846 * (double)j / 1024.0;
        tw[j] = make_float2((float)cos(ang), (float)sin(ang));
    }
    if (j < NB) cnt[j] = 0;
}

// ---------------------------------------------------------------- STFT power
// one block per (frame-pair, batch); two real frames packed into one complex
// 1024-pt radix-2 DIT FFT in LDS, unpacked via conjugate symmetry.
__global__ __launch_bounds__(256) void stft_power_kernel(
        const float* __restrict__ y, const float2* __restrict__ twg,
        float* __restrict__ Y) {
    __shared__ float re[1024];
    __shared__ float im[1024];
    __shared__ float twc[512];
    __shared__ float tws[512];

    const int g = blockIdx.x;       // frame pair
    const int b = blockIdx.y;       // batch
    const int tid = threadIdx.x;
    const int f0 = 2 * g;
    const int f1 = f0 + 1;
    const bool has1 = (f1 < TT);

    for (int j = tid; j < 512; j += 256) {
        float2 t = twg[j];
        twc[j] = t.x; tws[j] = t.y;
    }

    const float* yb = y + (size_t)b * TLEN;
    for (int i = tid; i < 1024; i += 256) {
        int n = (int)(__brev((unsigned)i) >> 22);   // 10-bit reverse
        float v0 = 0.0f, v1 = 0.0f;
        if (n >= 112 && n < 912) {                  // centered 800-tap hann
            float nf = (float)(n - 112);
            float arg = (6.2831855f * nf) / 800.0f;
            float w = 0.5f - 0.5f * cosf(arg);
            int p0 = f0 * HOP + n - 512;            // reflect pad K/2 = 512
            int q0 = p0 < 0 ? -p0 : (p0 >= TLEN ? 2 * TLEN - 2 - p0 : p0);
            v0 = yb[q0] * w;
            if (has1) {
                int p1 = p0 + HOP;
                int q1 = p1 < 0 ? -p1 : (p1 >= TLEN ? 2 * TLEN - 2 - p1 : p1);
                v1 = yb[q1] * w;
            }
        }
        re[i] = v0;
        im[i] = v1;
    }
    __syncthreads();

    for (int s = 0; s < 10; ++s) {
        const int half = 1 << s;
        for (int k = tid; k < 512; k += 256) {
            int j  = k & (half - 1);
            int i0 = ((k >> s) << (s + 1)) | j;
            int i1 = i0 + half;
            int tj = j << (9 - s);
            float c = twc[tj], sn = tws[tj];
            float ar = re[i0], ai = im[i0];
            float br = re[i1], bi = im[i1];
            float tr = br * c - bi * sn;
            float ti = br * sn + bi * c;
            re[i0] = ar + tr; im[i0] = ai + ti;
            re[i1] = ar - tr; im[i1] = ai - ti;
        }
        __syncthreads();
    }

    // unpack two real spectra; bins 0..255, layout Y[b][bin][frame]
    const int k = tid;
    const int nk = (1024 - k) & 1023;
    float zr = re[k],  zi = im[k];
    float wr = re[nk], wi = im[nk];
    float x0r = 0.5f * (zr + wr), x0i = 0.5f * (zi - wi);
    float x1r = 0.5f * (zi + wi), x1i = 0.5f * (wr - zr);
    float* yrow = Y + ((size_t)b * NBINS + k) * TT;
    yrow[f0] = x0r * x0r + x0i * x0i;
    if (has1) yrow[f1] = x1r * x1r + x1i * x1i;
}

// ---------------------------------------------------------------- per-subband
// one block per (b,f). dec flags packed via ballot; runlen = trailing ones of
// a 12-bit window. Valid keys compacted in LDS, ONE global atomic per block.
__global__ __launch_bounds__(256) void subband_kernel(
        const float* __restrict__ Y, unsigned* __restrict__ compact,
        int* __restrict__ cnt) {
    __shared__ float ys[TT];
    __shared__ unsigned lkeys[TT];
    __shared__ unsigned long long decw[5];
    __shared__ int wmax[4];
    __shared__ int maxrun_s;
    __shared__ int lcnt, gbase;

    const int tid = threadIdx.x;
    const int lane = tid & 63;
    const int wave = tid >> 6;
    const int b = blockIdx.x >> 8;          // 256 subbands per batch
    const float* row = Y + (size_t)blockIdx.x * TT;

    if (tid == 0) lcnt = 0;
    for (int t = tid; t < TT; t += 256) ys[t] = row[t];
    __syncthreads();

    // dec[t] = ys[t+1] < ys[t], packed 64/wave via ballot
    for (int c = wave; c < 5; c += 4) {
        int t = c * 64 + lane;
        bool d = (t < TT - 1) && (ys[t + 1] < ys[t]);
        unsigned long long m = __ballot(d);
        if (lane == 0) decw[c] = m;
    }
    __syncthreads();

    auto runlen = [&](int t) -> int {
        int w = t >> 6, off = t & 63;
        unsigned long long lo = decw[w] >> off;
        if (off && w < 4) lo |= decw[w + 1] << (64 - off);
        unsigned win = (unsigned)lo & 0xFFFu;
        return (win == 0xFFFu) ? 12 : (__ffs(~win) - 1);
    };

    const int rl0 = runlen(tid);
    const int rl1 = (tid + 256 < TT) ? runlen(tid + 256) : 0;

    int m = max(rl0, rl1);
    #pragma unroll
    for (int o = 32; o; o >>= 1) m = max(m, __shfl_xor(m, o));
    if (lane == 0) wmax[wave] = m;
    __syncthreads();
    if (tid == 0)
        maxrun_s = max(max(wmax[0], wmax[1]), max(wmax[2], wmax[3]));
    __syncthreads();

    const int maxrun = maxrun_s;            // capped at 12
    if (maxrun < 2) return;                 // has_any == false
    const int L = maxrun + 1;               // == min(13, true_maxrun+1)

    float sumx = 0.0f;
    #pragma unroll
    for (int j = 0; j < LMAX; ++j) if (j < L) sumx += (float)j;
    const float xm = sumx / (float)L;
    float den = 0.0f;
    #pragma unroll
    for (int j = 0; j < LMAX; ++j) if (j < L) { float xc = (float)j - xm; den += xc * xc; }

    for (int t = tid; t < TT; t += 256) {
        const int rl = (t == tid) ? rl0 : rl1;
        if (rl >= L - 1) {                  // start_mask (t+L<=T implied)
            float edc[LMAX];
            float s = 0.0f;
            #pragma unroll
            for (int j = LMAX - 1; j >= 0; --j) {
                if (j < L) s += ys[t + j];
                edc[j] = s;
            }
            float db0 = 10.0f * log10f(fmaxf(edc[0], 1e-10f));
            float scl[LMAX];
            float s1 = 0.0f;
            float last = 0.0f;
            #pragma unroll
            for (int j = 0; j < LMAX; ++j) {
                if (j < L) {
                    float db = 10.0f * log10f(fmaxf(edc[j], 1e-10f));
                    float sc = db - db0;
                    scl[j] = sc;
                    s1 += sc;
                    if (j == L - 1) last = sc;
                }
            }
            if (last < -10.0f) {            // selected
                const float ym = s1 / (float)L;
                float num = 0.0f;
                #pragma unroll
                for (int j = 0; j < LMAX; ++j)
                    if (j < L) num += ((float)j - xm) * (scl[j] - ym);
                const float slope = num / den;
                float rt60 = (-60.0f / slope) * 0.0375f;   // * HOP/FS
                int idx = atomicAdd(&lcnt, 1);
                lkeys[idx] = f2key(rt60);
            }
        }
    }
    __syncthreads();

    const int nloc = lcnt;
    if (nloc == 0) return;
    if (tid == 0) gbase = atomicAdd(&cnt[b], nloc);
    __syncthreads();
    unsigned* dst = compact + (size_t)b * NTOT + gbase;
    for (int i = tid; i < nloc; i += 256) dst[i] = lkeys[i];
}

// ---------------------------------------------------------------- median
// one block per batch: exact k-th smallest of cnt[b] compacted keys via
// 3-pass (14+14+4 bit) LDS-histogram radix select.
__global__ __launch_bounds__(256) void median_kernel(
        const unsigned* __restrict__ compact, const int* __restrict__ cnt,
        const float* __restrict__ coeffs, float* __restrict__ out) {
    __shared__ unsigned hist[16384];
    __shared__ unsigned csum[256];
    __shared__ unsigned sh_kk, sh_prefix, sh_pmask;

    const int b = blockIdx.x;
    const int tid = threadIdx.x;
    const int n = min(cnt[b], NTOT);
    const unsigned* kb = compact + (size_t)b * NTOT;

    if (tid == 0) {
        sh_kk = (n > 0) ? (unsigned)((n - 1) / 2) : 0u;
        sh_prefix = 0u; sh_pmask = 0u;
    }
    __syncthreads();

    const int shifts[3] = {18, 4, 0};
    const int nbins_[3] = {16384, 16384, 16};

    for (int p = 0; p < 3; ++p) {
        const int shift = shifts[p];
        const unsigned nb = (unsigned)nbins_[p];
        const unsigned bmask = nb - 1u;

        for (int i = tid; i < (int)nb; i += 256) hist[i] = 0u;
        __syncthreads();

        const unsigned pfx = sh_prefix, pm = sh_pmask;
        for (int i = tid; i < n; i += 256) {
            unsigned k = kb[i];
            if ((k & pm) == pfx) atomicAdd(&hist[(k >> shift) & bmask], 1u);
        }
        __syncthreads();

        if (nb >= 256u) {
            const int csz = (int)(nb >> 8);
            unsigned s = 0;
            for (int i = 0; i < csz; ++i) s += hist[tid * csz + i];
            csum[tid] = s;
        }
        __syncthreads();

        if (tid == 0) {
            unsigned kk = sh_kk, cum = 0, sel = 0;
            if (nb >= 256u) {
                const int csz = (int)(nb >> 8);
                int c = 255;
                for (int i = 0; i < 256; ++i) {
                    unsigned h = csum[i];
                    if (kk < cum + h) { c = i; break; }
                    cum += h;
                }
                for (int i = 0; i < csz; ++i) {
                    unsigned h = hist[c * csz + i];
                    if (kk < cum + h) { sel = (unsigned)(c * csz + i); break; }
                    cum += h;
                }
            } else {
                for (unsigned i = 0; i < nb; ++i) {
                    unsigned h = hist[i];
                    if (kk < cum + h) { sel = i; break; }
                    cum += h;
                }
            }
            sh_kk = kk - cum;
            sh_prefix = sh_prefix | (sel << shift);
            sh_pmask = sh_pmask | (bmask << shift);
        }
        __syncthreads();
    }

    if (tid == 0) {
        unsigned kx = sh_prefix;
        unsigned fb = (kx & 0x80000000u) ? (kx & 0x7FFFFFFFu) : ~kx;
        float med = __uint_as_float(fb);
        float o = (n > 0) ? (coeffs[0] + coeffs[1] * med) : 0.5f;
        out[b] = fmaxf(o, 0.01f);
    }
}

// ----------------------------------------------------------------
extern "C" void kernel_launch(void* const* d_in, const int* in_sizes, int n_in,
                              void* d_out, int out_size, void* d_ws, size_t ws_size,
                              hipStream_t stream) {
    const float* y = (const float*)d_in[0];
    const float* coeffs = (const float*)d_in[1];
    float* out = (float*)d_out;

    // ws layout:
    //   [0]        Y       : NB*NBINS*TT floats = 8,749,056 B
    //   [YB]       compact : NB*NTOT uints      = 8,749,056 B
    //   [2*YB]     cnt     : NB ints (zeroed by twiddle_init)
    //   [..+128]   tw      : 512 float2
    const size_t YB = (size_t)NB * NBINS * TT * sizeof(float);
    char* base = (char*)d_ws;
    float* Y = (float*)base;
    unsigned* compact = (unsigned*)(base + YB);
    int* cnt = (int*)(base + 2 * YB);
    float2* tw = (float2*)(base + 2 * YB + 128);

    twiddle_init_kernel<<<2, 256, 0, stream>>>(tw, cnt);
    stft_power_kernel<<<dim3((TT + 1) / 2, NB), 256, 0, stream>>>(y, tw, Y);
    subband_kernel<<<NB * NBINS, 256, 0, stream>>>(Y, compact, cnt);
    median_kernel<<<NB, 256, 0, stream>>>(compact, cnt, coeffs, out);
}

// Round 5
// 144.332 us; speedup vs baseline: 2.2910x; 1.6306x over previous
//
#include <hip/hip_runtime.h>
#include <hip/hip_bf16.h>
#include <math.h>

#define NB 32          // batch
#define TLEN 160000    // samples per batch
#define KFFT 1024      // n_fft
#define HOP 600
#define NBINS 256
#define TT 267         // frames: 1 + (160000+1024-1024)/600
#define NROWS (NB * NBINS)  // 8192
#define LMAX 13
#define LMIN 3

__device__ __forceinline__ unsigned f2key(float f) {
    unsigned b = __float_as_uint(f);
    return (b & 0x80000000u) ? ~b : (b | 0x80000000u);
}

// LDS anti-bank-conflict swizzle for the FFT arrays
__device__ __forceinline__ int P(int i) { return i + (i >> 4); }

// ---------------------------------------------------------------- twiddles
__global__ void twiddle_init_kernel(float2* __restrict__ tw) {
    int j = blockIdx.x * blockDim.x + threadIdx.x;
    if (j < 512) {
        double ang = -2.0 * 3.14159265358979323846 * (double)j / 1024.0;
        tw[j] = make_float2((float)cos(ang), (float)sin(ang));
    }
}

// ---------------------------------------------------------------- STFT power
// one block per (frame-pair, batch); two real frames packed as one complex
// 1024-pt FFT; radix-2 stage PAIRS fused into register radix-4 (5 barriers).
__global__ __launch_bounds__(256) void stft_power_kernel(
        const float* __restrict__ y, const float2* __restrict__ twg,
        float* __restrict__ Y) {
    __shared__ float2 z[1024 + 64];
    __shared__ float2 twl[512 + 32];

    const int g = blockIdx.x;       // frame pair
    const int b = blockIdx.y;       // batch
    const int tid = threadIdx.x;
    const int f0 = 2 * g;
    const int f1 = f0 + 1;
    const bool has1 = (f1 < TT);

    for (int j = tid; j < 512; j += 256) twl[P(j)] = twg[j];

    const float* yb = y + (size_t)b * TLEN;
    for (int i = tid; i < 1024; i += 256) {
        int n = (int)(__brev((unsigned)i) >> 22);   // 10-bit reverse
        float v0 = 0.0f, v1 = 0.0f;
        if (n >= 112 && n < 912) {                  // centered 800-tap hann
            float nf = (float)(n - 112);
            float arg = (6.2831855f * nf) / 800.0f;
            float w = 0.5f - 0.5f * cosf(arg);
            int p0 = f0 * HOP + n - 512;            // reflect pad K/2 = 512
            int q0 = p0 < 0 ? -p0 : (p0 >= TLEN ? 2 * TLEN - 2 - p0 : p0);
            v0 = yb[q0] * w;
            if (has1) {
                int p1 = p0 + HOP;
                int q1 = p1 < 0 ? -p1 : (p1 >= TLEN ? 2 * TLEN - 2 - p1 : p1);
                v1 = yb[q1] * w;
            }
        }
        z[P(i)] = make_float2(v0, v1);
    }
    __syncthreads();

    // 5 fused double-stages (radix-2 pairs (0,1),(2,3),...,(8,9))
    #pragma unroll
    for (int s = 0; s < 10; s += 2) {
        const int h = 1 << s;
        const int j = tid & (h - 1);
        const int i0 = ((tid >> s) << (s + 2)) | j;
        float2 a0 = z[P(i0)];
        float2 a1 = z[P(i0 + h)];
        float2 a2 = z[P(i0 + 2 * h)];
        float2 a3 = z[P(i0 + 3 * h)];
        float2 w  = twl[P(j << (9 - s))];
        float2 u0 = twl[P(j << (8 - s))];
        float2 u1 = twl[P((j + h) << (8 - s))];
        // stage s: (a0,a1) and (a2,a3), twiddle w
        float t1r = w.x * a1.x - w.y * a1.y, t1i = w.x * a1.y + w.y * a1.x;
        float t3r = w.x * a3.x - w.y * a3.y, t3i = w.x * a3.y + w.y * a3.x;
        float b0r = a0.x + t1r, b0i = a0.y + t1i;
        float b1r = a0.x - t1r, b1i = a0.y - t1i;
        float b2r = a2.x + t3r, b2i = a2.y + t3i;
        float b3r = a2.x - t3r, b3i = a2.y - t3i;
        // stage s+1: (b0,b2) w/u0, (b1,b3) w/u1
        float c0r = u0.x * b2r - u0.y * b2i, c0i = u0.x * b2i + u0.y * b2r;
        float c1r = u1.x * b3r - u1.y * b3i, c1i = u1.x * b3i + u1.y * b3r;
        z[P(i0)]         = make_float2(b0r + c0r, b0i + c0i);
        z[P(i0 + h)]     = make_float2(b1r + c1r, b1i + c1i);
        z[P(i0 + 2 * h)] = make_float2(b0r - c0r, b0i - c0i);
        z[P(i0 + 3 * h)] = make_float2(b1r - c1r, b1i - c1i);
        __syncthreads();
    }

    // unpack two real spectra; bins 0..255, layout Y[b][bin][frame]
    const int k = tid;
    const int nk = (1024 - k) & 1023;
    float2 zk = z[P(k)], zn = z[P(nk)];
    float x0r = 0.5f * (zk.x + zn.x), x0i = 0.5f * (zk.y - zn.y);
    float x1r = 0.5f * (zk.y + zn.y), x1i = 0.5f * (zn.x - zk.x);
    float* yrow = Y + ((size_t)b * NBINS + k) * TT;
    yrow[f0] = x0r * x0r + x0i * x0i;
    if (has1) yrow[f1] = x1r * x1r + x1i * x1i;
}

// ---------------------------------------------------------------- per-subband
// ONE ROW PER WAVE (2048 blocks x 4 waves). dec flags in ballot registers,
// wave-local compaction, private per-row output region, NO atomics,
// a single __syncthreads (staging).
__global__ __launch_bounds__(256) void subband_kernel(
        const float* __restrict__ Y, unsigned* __restrict__ compact,
        int* __restrict__ rowcnt) {
    __shared__ float ys[4][272];

    const int tid = threadIdx.x;
    const int lane = tid & 63;
    const int wave = tid >> 6;
    const int row = blockIdx.x * 4 + wave;
    const float* src = Y + (size_t)row * TT;

    float v[5];
    #pragma unroll
    for (int c = 0; c < 5; ++c) {
        int t = c * 64 + lane;
        v[c] = (t < TT) ? src[t] : 0.0f;
        if (t < TT) ys[wave][t] = v[c];
    }
    __syncthreads();                 // the only barrier

    const float* yy = ys[wave];

    // dec[t] = yy[t+1] < yy[t], 64 flags per ballot, kept in registers
    unsigned long long m[5];
    #pragma unroll
    for (int c = 0; c < 5; ++c) {
        int t = c * 64 + lane;
        bool d = (t < TT - 1) && (yy[t + 1] < v[c]);
        m[c] = __ballot(d);
    }

    // runlen(t) capped at 12 = trailing ones of dec[t..t+11]
    auto runl = [&](int c, int l) -> int {
        unsigned long long lo = m[c] >> l;
        if (l && c < 4) lo |= m[c + 1] << (64 - l);
        unsigned win = (unsigned)lo & 0xFFFu;
        return (win == 0xFFFu) ? 12 : (__ffs((int)~win) - 1);
    };

    int rl[5];
    int mx = 0;
    #pragma unroll
    for (int c = 0; c < 5; ++c) { rl[c] = runl(c, lane); mx = max(mx, rl[c]); }
    #pragma unroll
    for (int o = 32; o; o >>= 1) mx = max(mx, __shfl_xor(mx, o));
    const int maxrun = mx;           // capped at 12, uniform across wave

    if (maxrun < 2) {                // has_any == false
        if (lane == 0) rowcnt[row] = 0;
        return;
    }
    const int L = maxrun + 1;        // == min(13, true_maxrun+1)

    float sumx = 0.0f;
    #pragma unroll
    for (int j = 0; j < LMAX; ++j) if (j < L) sumx += (float)j;
    const float xm = sumx / (float)L;
    float den = 0.0f;
    #pragma unroll
    for (int j = 0; j < LMAX; ++j) if (j < L) { float xc = (float)j - xm; den += xc * xc; }

    unsigned keys[5];
    unsigned long long vm[5];
    #pragma unroll
    for (int c = 0; c < 5; ++c) {
        const int t = c * 64 + lane;
        bool sel = false;
        unsigned key = 0u;
        if (rl[c] >= L - 1) {        // start_mask (t+L<=T implied by run len)
            float edc[LMAX];
            float s = 0.0f;
            #pragma unroll
            for (int j = LMAX - 1; j >= 0; --j) {
                if (j < L) s += yy[t + j];
                edc[j] = s;
            }
            float db0 = 10.0f * log10f(fmaxf(edc[0], 1e-10f));
            float scl[LMAX];
            float s1 = 0.0f;
            float last = 0.0f;
            #pragma unroll
            for (int j = 0; j < LMAX; ++j) {
                if (j < L) {
                    float db = 10.0f * log10f(fmaxf(edc[j], 1e-10f));
                    float sc = db - db0;
                    scl[j] = sc;
                    s1 += sc;
                    if (j == L - 1) last = sc;
                }
            }
            if (last < -10.0f) {     // selected
                const float ym = s1 / (float)L;
                float num = 0.0f;
                #pragma unroll
                for (int j = 0; j < LMAX; ++j)
                    if (j < L) num += ((float)j - xm) * (scl[j] - ym);
                const float slope = num / den;
                float rt60 = (-60.0f / slope) * 0.0375f;   // * HOP/FS
                sel = true;
                key = f2key(rt60);
            }
        }
        vm[c] = __ballot(sel);       // uniform point
        keys[c] = key;
    }

    // wave-local compaction into the row's private region
    unsigned* dst = compact + (size_t)row * TT;
    const unsigned long long below = (1ull << lane) - 1ull;
    int base = 0;
    #pragma unroll
    for (int c = 0; c < 5; ++c) {
        if (vm[c] & (1ull << lane))
            dst[base + (int)__popcll(vm[c] & below)] = keys[c];
        base += (int)__popcll(vm[c]);
    }
    if (lane == 0) rowcnt[row] = base;
}

// ---------------------------------------------------------------- median
// one block per batch: sum 256 row counts, then exact k-th smallest via
// 3-pass (14+14+4 bit) LDS-histogram radix select over rowwise regions.
__global__ __launch_bounds__(256) void median_kernel(
        const unsigned* __restrict__ compact, const int* __restrict__ rowcnt,
        const float* __restrict__ coeffs, float* __restrict__ out) {
    __shared__ unsigned hist[16384];
    __shared__ unsigned csum[256];
    __shared__ int red[256];
    __shared__ unsigned sh_kk, sh_prefix, sh_pmask;

    const int b = blockIdx.x;
    const int tid = threadIdx.x;
    const int myrow = b * NBINS + tid;
    const int myc = rowcnt[myrow];
    const unsigned* mykeys = compact + (size_t)myrow * TT;

    red[tid] = myc;
    __syncthreads();
    for (int s = 128; s > 0; s >>= 1) {
        if (tid < s) red[tid] += red[tid + s];
        __syncthreads();
    }
    const int n = red[0];
    __syncthreads();

    if (tid == 0) {
        sh_kk = (n > 0) ? (unsigned)((n - 1) / 2) : 0u;
        sh_prefix = 0u; sh_pmask = 0u;
    }
    __syncthreads();

    const int shifts[3] = {18, 4, 0};
    const int nbins_[3] = {16384, 16384, 16};

    for (int p = 0; p < 3; ++p) {
        const int shift = shifts[p];
        const unsigned nbn = (unsigned)nbins_[p];
        const unsigned bmask = nbn - 1u;

        for (int i = tid; i < (int)nbn; i += 256) hist[i] = 0u;
        __syncthreads();

        const unsigned pfx = sh_prefix, pm = sh_pmask;
        for (int i = 0; i < myc; ++i) {
            unsigned k = mykeys[i];
            if ((k & pm) == pfx) atomicAdd(&hist[(k >> shift) & bmask], 1u);
        }
        __syncthreads();

        if (nbn >= 256u) {
            const int csz = (int)(nbn >> 8);
            unsigned s = 0;
            for (int i = 0; i < csz; ++i) s += hist[tid * csz + i];
            csum[tid] = s;
        }
        __syncthreads();

        if (tid == 0) {
            unsigned kk = sh_kk, cum = 0, sel = 0;
            if (nbn >= 256u) {
                const int csz = (int)(nbn >> 8);
                int c = 255;
                for (int i = 0; i < 256; ++i) {
                    unsigned h = csum[i];
                    if (kk < cum + h) { c = i; break; }
                    cum += h;
                }
                for (int i = 0; i < csz; ++i) {
                    unsigned h = hist[c * csz + i];
                    if (kk < cum + h) { sel = (unsigned)(c * csz + i); break; }
                    cum += h;
                }
            } else {
                for (unsigned i = 0; i < nbn; ++i) {
                    unsigned h = hist[i];
                    if (kk < cum + h) { sel = i; break; }
                    cum += h;
                }
            }
            sh_kk = kk - cum;
            sh_prefix = sh_prefix | (sel << shift);
            sh_pmask = sh_pmask | (bmask << shift);
        }
        __syncthreads();
    }

    if (tid == 0) {
        unsigned kx = sh_prefix;
        unsigned fb = (kx & 0x80000000u) ? (kx & 0x7FFFFFFFu) : ~kx;
        float med = __uint_as_float(fb);
        float o = (n > 0) ? (coeffs[0] + coeffs[1] * med) : 0.5f;
        out[b] = fmaxf(o, 0.01f);
    }
}

// ----------------------------------------------------------------
extern "C" void kernel_launch(void* const* d_in, const int* in_sizes, int n_in,
                              void* d_out, int out_size, void* d_ws, size_t ws_size,
                              hipStream_t stream) {
    const float* y = (const float*)d_in[0];
    const float* coeffs = (const float*)d_in[1];
    float* out = (float*)d_out;

    // ws layout:
    //   [0]        Y       : NROWS*TT floats = 8,749,056 B
    //   [YB]       compact : NROWS*TT uints  = 8,749,056 B (per-row 267 slots)
    //   [2*YB]     rowcnt  : NROWS ints      = 32 KB (fully overwritten per call)
    //   [..]       tw      : 512 float2
    const size_t YB = (size_t)NROWS * TT * sizeof(float);
    char* base = (char*)d_ws;
    float* Y = (float*)base;
    unsigned* compact = (unsigned*)(base + YB);
    int* rowcnt = (int*)(base + 2 * YB);
    float2* tw = (float2*)(base + 2 * YB + (size_t)NROWS * sizeof(int));

    twiddle_init_kernel<<<2, 256, 0, stream>>>(tw);
    stft_power_kernel<<<dim3((TT + 1) / 2, NB), 256, 0, stream>>>(y, tw, Y);
    subband_kernel<<<NROWS / 4, 256, 0, stream>>>(Y, compact, rowcnt);
    median_kernel<<<NB, 256, 0, stream>>>(compact, rowcnt, coeffs, out);
}

// Round 6
// 139.512 us; speedup vs baseline: 2.3702x; 1.0345x over previous
//
#include <hip/hip_runtime.h>
#include <hip/hip_bf16.h>
#include <math.h>

#define NB 32          // batch
#define TLEN 160000    // samples per batch
#define KFFT 1024      // n_fft
#define HOP 600
#define NBINS 256
#define TT 267         // frames: 1 + (160000+1024-1024)/600
#define NROWS (NB * NBINS)  // 8192
#define LMAX 13
#define LMIN 3

__device__ __forceinline__ unsigned f2key(float f) {
    unsigned b = __float_as_uint(f);
    return (b & 0x80000000u) ? ~b : (b | 0x80000000u);
}

// LDS anti-bank-conflict swizzle for the FFT arrays
__device__ __forceinline__ int P(int i) { return i + (i >> 4); }

// ---------------------------------------------------------------- init: twiddles + window
__global__ void init_kernel(float2* __restrict__ tw, float* __restrict__ wtab) {
    int j = blockIdx.x * blockDim.x + threadIdx.x;
    if (j < 512) {
        double ang = -2.0 * 3.14159265358979323846 * (double)j / 1024.0;
        tw[j] = make_float2((float)cos(ang), (float)sin(ang));
    }
    if (j < 800) {
        float arg = (6.2831855f * (float)j) / 800.0f;   // same f32 expr as before
        wtab[j] = 0.5f - 0.5f * cosf(arg);
    }
}

// ---------------------------------------------------------------- STFT power
// one block per (frame-pair, batch); two real frames packed as one complex
// 1024-pt DIF FFT (natural-order input -> COALESCED global loads; bit-reversed
// output resolved by LDS lookup). Radix-2 stage pairs fused to radix-4.
__global__ __launch_bounds__(256) void stft_power_kernel(
        const float* __restrict__ y, const float2* __restrict__ twg,
        const float* __restrict__ wtab, float* __restrict__ Y) {
    __shared__ float2 z[1024 + 64];
    __shared__ float2 twl[512 + 32];

    const int g = blockIdx.x;       // frame pair
    const int b = blockIdx.y;       // batch
    const int tid = threadIdx.x;
    const int f0 = 2 * g;
    const int f1 = f0 + 1;
    const bool has1 = (f1 < TT);

    for (int j = tid; j < 512; j += 256) twl[P(j)] = twg[j];

    const float* yb = y + (size_t)b * TLEN;
    const int base = f0 * HOP - 512;            // reflect pad K/2 = 512
    for (int i = tid; i < 1024; i += 256) {
        float v0 = 0.0f, v1 = 0.0f;
        if (i >= 112 && i < 912) {              // centered 800-tap hann
            float w = wtab[i - 112];
            int p0 = base + i;
            int q0 = p0 < 0 ? -p0 : (p0 >= TLEN ? 2 * TLEN - 2 - p0 : p0);
            v0 = yb[q0] * w;                    // coalesced
            if (has1) {
                int p1 = p0 + HOP;
                int q1 = p1 < 0 ? -p1 : (p1 >= TLEN ? 2 * TLEN - 2 - p1 : p1);
                v1 = yb[q1] * w;                // coalesced
            }
        }
        z[P(i)] = make_float2(v0, v1);
    }
    __syncthreads();

    // 5 fused DIF double-stages: q = 256,64,16,4,1
    #pragma unroll
    for (int s = 8; s >= 0; s -= 2) {
        const int q = 1 << s;
        const int j = tid & (q - 1);
        const int i0 = ((tid >> s) << (s + 2)) | j;
        float2 a0 = z[P(i0)];
        float2 a1 = z[P(i0 + q)];
        float2 a2 = z[P(i0 + 2 * q)];
        float2 a3 = z[P(i0 + 3 * q)];
        float2 u  = twl[P(j << (8 - s))];   // W^{j*256/q}
        float2 w2 = twl[P(j << (9 - s))];   // W^{j*512/q}
        // outer stage (half 2q)
        float b0r = a0.x + a2.x, b0i = a0.y + a2.y;
        float b1r = a1.x + a3.x, b1i = a1.y + a3.y;
        float t2r = a0.x - a2.x, t2i = a0.y - a2.y;
        float t3r = a1.x - a3.x, t3i = a1.y - a3.y;
        float b2r = t2r * u.x - t2i * u.y, b2i = t2r * u.y + t2i * u.x;
        float m3r = t3r * u.x - t3i * u.y, m3i = t3r * u.y + t3i * u.x;
        float b3r = m3i, b3i = -m3r;        // *(W^256) = *(-i)
        // inner stage (half q)
        float2 c0 = make_float2(b0r + b1r, b0i + b1i);
        float d1r = b0r - b1r, d1i = b0i - b1i;
        float2 c1 = make_float2(d1r * w2.x - d1i * w2.y, d1r * w2.y + d1i * w2.x);
        float2 c2 = make_float2(b2r + b3r, b2i + b3i);
        float d3r = b2r - b3r, d3i = b2i - b3i;
        float2 c3 = make_float2(d3r * w2.x - d3i * w2.y, d3r * w2.y + d3i * w2.x);
        z[P(i0)]         = c0;
        z[P(i0 + q)]     = c1;
        z[P(i0 + 2 * q)] = c2;
        z[P(i0 + 3 * q)] = c3;
        __syncthreads();
    }

    // output is bit-reversed: Z[k] sits at z[brev10(k)]
    const int k = tid;
    const int nk = (1024 - k) & 1023;
    const int rk = (int)(__brev((unsigned)k) >> 22);
    const int rn = (int)(__brev((unsigned)nk) >> 22);
    float2 zk = z[P(rk)], zn = z[P(rn)];
    float x0r = 0.5f * (zk.x + zn.x), x0i = 0.5f * (zk.y - zn.y);
    float x1r = 0.5f * (zk.y + zn.y), x1i = 0.5f * (zn.x - zk.x);
    float* yrow = Y + ((size_t)b * NBINS + k) * TT;
    yrow[f0] = x0r * x0r + x0i * x0i;
    if (has1) yrow[f1] = x1r * x1r + x1i * x1i;
}

// ---------------------------------------------------------------- per-subband
// ONE ROW PER WAVE (2048 blocks x 4 waves). dec flags in ballot registers,
// wave-local compaction, private per-row output region, NO atomics,
// a single __syncthreads (staging).
__global__ __launch_bounds__(256) void subband_kernel(
        const float* __restrict__ Y, unsigned* __restrict__ compact,
        int* __restrict__ rowcnt) {
    __shared__ float ys[4][272];

    const int tid = threadIdx.x;
    const int lane = tid & 63;
    const int wave = tid >> 6;
    const int row = blockIdx.x * 4 + wave;
    const float* src = Y + (size_t)row * TT;

    float v[5];
    #pragma unroll
    for (int c = 0; c < 5; ++c) {
        int t = c * 64 + lane;
        v[c] = (t < TT) ? src[t] : 0.0f;
        if (t < TT) ys[wave][t] = v[c];
    }
    __syncthreads();                 // the only barrier

    const float* yy = ys[wave];

    unsigned long long m[5];
    #pragma unroll
    for (int c = 0; c < 5; ++c) {
        int t = c * 64 + lane;
        bool d = (t < TT - 1) && (yy[t + 1] < v[c]);
        m[c] = __ballot(d);
    }

    auto runl = [&](int c, int l) -> int {
        unsigned long long lo = m[c] >> l;
        if (l && c < 4) lo |= m[c + 1] << (64 - l);
        unsigned win = (unsigned)lo & 0xFFFu;
        return (win == 0xFFFu) ? 12 : (__ffs((int)~win) - 1);
    };

    int rl[5];
    int mx = 0;
    #pragma unroll
    for (int c = 0; c < 5; ++c) { rl[c] = runl(c, lane); mx = max(mx, rl[c]); }
    #pragma unroll
    for (int o = 32; o; o >>= 1) mx = max(mx, __shfl_xor(mx, o));
    const int maxrun = mx;           // capped at 12, uniform across wave

    if (maxrun < 2) {                // has_any == false
        if (lane == 0) rowcnt[row] = 0;
        return;
    }
    const int L = maxrun + 1;        // == min(13, true_maxrun+1)

    float sumx = 0.0f;
    #pragma unroll
    for (int j = 0; j < LMAX; ++j) if (j < L) sumx += (float)j;
    const float xm = sumx / (float)L;
    float den = 0.0f;
    #pragma unroll
    for (int j = 0; j < LMAX; ++j) if (j < L) { float xc = (float)j - xm; den += xc * xc; }

    unsigned keys[5];
    unsigned long long vm[5];
    #pragma unroll
    for (int c = 0; c < 5; ++c) {
        const int t = c * 64 + lane;
        bool sel = false;
        unsigned key = 0u;
        if (rl[c] >= L - 1) {        // start_mask (t+L<=T implied by run len)
            float edc[LMAX];
            float s = 0.0f;
            #pragma unroll
            for (int j = LMAX - 1; j >= 0; --j) {
                if (j < L) s += yy[t + j];
                edc[j] = s;
            }
            float db0 = 10.0f * log10f(fmaxf(edc[0], 1e-10f));
            float scl[LMAX];
            float s1 = 0.0f;
            float last = 0.0f;
            #pragma unroll
            for (int j = 0; j < LMAX; ++j) {
                if (j < L) {
                    float db = 10.0f * log10f(fmaxf(edc[j], 1e-10f));
                    float sc = db - db0;
                    scl[j] = sc;
                    s1 += sc;
                    if (j == L - 1) last = sc;
                }
            }
            if (last < -10.0f) {     // selected
                const float ym = s1 / (float)L;
                float num = 0.0f;
                #pragma unroll
                for (int j = 0; j < LMAX; ++j)
                    if (j < L) num += ((float)j - xm) * (scl[j] - ym);
                const float slope = num / den;
                float rt60 = (-60.0f / slope) * 0.0375f;   // * HOP/FS
                sel = true;
                key = f2key(rt60);
            }
        }
        vm[c] = __ballot(sel);       // uniform point
        keys[c] = key;
    }

    unsigned* dst = compact + (size_t)row * TT;
    const unsigned long long below = (1ull << lane) - 1ull;
    int base = 0;
    #pragma unroll
    for (int c = 0; c < 5; ++c) {
        if (vm[c] & (1ull << lane))
            dst[base + (int)__popcll(vm[c] & below)] = keys[c];
        base += (int)__popcll(vm[c]);
    }
    if (lane == 0) rowcnt[row] = base;
}

// ---------------------------------------------------------------- median
// one block per batch: sum 256 row counts, then exact k-th smallest via
// 3-pass (14+14+4 bit) LDS-histogram radix select over rowwise regions.
__global__ __launch_bounds__(256) void median_kernel(
        const unsigned* __restrict__ compact, const int* __restrict__ rowcnt,
        const float* __restrict__ coeffs, float* __restrict__ out) {
    __shared__ unsigned hist[16384];
    __shared__ unsigned csum[256];
    __shared__ int red[256];
    __shared__ unsigned sh_kk, sh_prefix, sh_pmask;

    const int b = blockIdx.x;
    const int tid = threadIdx.x;
    const int myrow = b * NBINS + tid;
    const int myc = rowcnt[myrow];
    const unsigned* mykeys = compact + (size_t)myrow * TT;

    red[tid] = myc;
    __syncthreads();
    for (int s = 128; s > 0; s >>= 1) {
        if (tid < s) red[tid] += red[tid + s];
        __syncthreads();
    }
    const int n = red[0];
    __syncthreads();

    if (tid == 0) {
        sh_kk = (n > 0) ? (unsigned)((n - 1) / 2) : 0u;
        sh_prefix = 0u; sh_pmask = 0u;
    }
    __syncthreads();

    const int shifts[3] = {18, 4, 0};
    const int nbins_[3] = {16384, 16384, 16};

    for (int p = 0; p < 3; ++p) {
        const int shift = shifts[p];
        const unsigned nbn = (unsigned)nbins_[p];
        const unsigned bmask = nbn - 1u;

        for (int i = tid; i < (int)nbn; i += 256) hist[i] = 0u;
        __syncthreads();

        const unsigned pfx = sh_prefix, pm = sh_pmask;
        for (int i = 0; i < myc; ++i) {
            unsigned k = mykeys[i];
            if ((k & pm) == pfx) atomicAdd(&hist[(k >> shift) & bmask], 1u);
        }
        __syncthreads();

        if (nbn >= 256u) {
            const int csz = (int)(nbn >> 8);
            unsigned s = 0;
            for (int i = 0; i < csz; ++i) s += hist[tid * csz + i];
            csum[tid] = s;
        }
        __syncthreads();

        if (tid == 0) {
            unsigned kk = sh_kk, cum = 0, sel = 0;
            if (nbn >= 256u) {
                const int csz = (int)(nbn >> 8);
                int c = 255;
                for (int i = 0; i < 256; ++i) {
                    unsigned h = csum[i];
                    if (kk < cum + h) { c = i; break; }
                    cum += h;
                }
                for (int i = 0; i < csz; ++i) {
                    unsigned h = hist[c * csz + i];
                    if (kk < cum + h) { sel = (unsigned)(c * csz + i); break; }
                    cum += h;
                }
            } else {
                for (unsigned i = 0; i < nbn; ++i) {
                    unsigned h = hist[i];
                    if (kk < cum + h) { sel = i; break; }
                    cum += h;
                }
            }
            sh_kk = kk - cum;
            sh_prefix = sh_prefix | (sel << shift);
            sh_pmask = sh_pmask | (bmask << shift);
        }
        __syncthreads();
    }

    if (tid == 0) {
        unsigned kx = sh_prefix;
        unsigned fb = (kx & 0x80000000u) ? (kx & 0x7FFFFFFFu) : ~kx;
        float med = __uint_as_float(fb);
        float o = (n > 0) ? (coeffs[0] + coeffs[1] * med) : 0.5f;
        out[b] = fmaxf(o, 0.01f);
    }
}

// ----------------------------------------------------------------
extern "C" void kernel_launch(void* const* d_in, const int* in_sizes, int n_in,
                              void* d_out, int out_size, void* d_ws, size_t ws_size,
                              hipStream_t stream) {
    const float* y = (const float*)d_in[0];
    const float* coeffs = (const float*)d_in[1];
    float* out = (float*)d_out;

    // ws layout:
    //   [0]        Y       : NROWS*TT floats = 8,749,056 B
    //   [YB]       compact : NROWS*TT uints  = 8,749,056 B (per-row 267 slots)
    //   [2*YB]     rowcnt  : NROWS ints      = 32 KB (fully overwritten per call)
    //   [..]       tw      : 512 float2
    //   [..]       wtab    : 800 floats
    const size_t YB = (size_t)NROWS * TT * sizeof(float);
    char* base = (char*)d_ws;
    float* Y = (float*)base;
    unsigned* compact = (unsigned*)(base + YB);
    int* rowcnt = (int*)(base + 2 * YB);
    float2* tw = (float2*)(base + 2 * YB + (size_t)NROWS * sizeof(int));
    float* wtab = (float*)((char*)tw + 512 * sizeof(float2));

    init_kernel<<<4, 256, 0, stream>>>(tw, wtab);
    stft_power_kernel<<<dim3((TT + 1) / 2, NB), 256, 0, stream>>>(y, tw, wtab, Y);
    subband_kernel<<<NROWS / 4, 256, 0, stream>>>(Y, compact, rowcnt);
    median_kernel<<<NB, 256, 0, stream>>>(compact, rowcnt, coeffs, out);
}

// Round 7
// 115.259 us; speedup vs baseline: 2.8689x; 1.2104x over previous
//
#include <hip/hip_runtime.h>
#include <hip/hip_bf16.h>
#include <math.h>

#define NB 32          // batch
#define TLEN 160000    // samples per batch
#define KFFT 1024      // n_fft
#define HOP 600
#define NBINS 256
#define TT 267         // frames: 1 + (160000+1024-1024)/600
#define NROWS (NB * NBINS)  // 8192
#define LMAX 13
#define LMIN 3

__device__ __forceinline__ unsigned f2key(float f) {
    unsigned b = __float_as_uint(f);
    return (b & 0x80000000u) ? ~b : (b | 0x80000000u);
}

// LDS anti-bank-conflict swizzle for the FFT arrays
__device__ __forceinline__ int P(int i) { return i + (i >> 4); }

// ---------------------------------------------------------------- init: twiddles + window
__global__ void init_kernel(float2* __restrict__ tw, float* __restrict__ wtab) {
    int j = blockIdx.x * blockDim.x + threadIdx.x;
    if (j < 512) {
        double ang = -2.0 * 3.14159265358979323846 * (double)j / 1024.0;
        tw[j] = make_float2((float)cos(ang), (float)sin(ang));
    }
    if (j < 800) {
        float arg = (6.2831855f * (float)j) / 800.0f;
        wtab[j] = 0.5f - 0.5f * cosf(arg);
    }
}

// ---------------------------------------------------------------- STFT power
// one block per (4 frames, batch): TWO complex 1024-pt DIF FFTs, each packing
// two real frames. Natural-order input (coalesced loads), bit-reversed output
// via LDS lookup. One barrier per fused double-stage serves both FFTs.
__global__ __launch_bounds__(256) void stft_power_kernel(
        const float* __restrict__ y, const float2* __restrict__ twg,
        const float* __restrict__ wtab, float* __restrict__ Y) {
    __shared__ float2 z[2][1024 + 64];
    __shared__ float2 twl[512 + 32];

    const int g = blockIdx.x;       // group of 4 frames
    const int b = blockIdx.y;
    const int tid = threadIdx.x;
    const int f0 = 4 * g;

    for (int j = tid; j < 512; j += 256) twl[P(j)] = twg[j];

    const float* yb = y + (size_t)b * TLEN;
    #pragma unroll
    for (int a = 0; a < 2; ++a) {
        const int fa = f0 + 2 * a;          // fa <= 266 < TT always
        const bool hasB = (fa + 1 < TT);
        const int base = fa * HOP - 512;    // reflect pad K/2 = 512
        for (int i = tid; i < 1024; i += 256) {
            float v0 = 0.0f, v1 = 0.0f;
            if (i >= 112 && i < 912) {      // centered 800-tap hann
                float w = wtab[i - 112];
                int p0 = base + i;
                int q0 = p0 < 0 ? -p0 : (p0 >= TLEN ? 2 * TLEN - 2 - p0 : p0);
                v0 = yb[q0] * w;            // coalesced
                if (hasB) {
                    int p1 = p0 + HOP;
                    int q1 = p1 < 0 ? -p1 : (p1 >= TLEN ? 2 * TLEN - 2 - p1 : p1);
                    v1 = yb[q1] * w;        // coalesced
                }
            }
            z[a][P(i)] = make_float2(v0, v1);
        }
    }
    __syncthreads();

    // 5 fused DIF double-stages: q = 256,64,16,4,1 (butterfly quads disjoint
    // per thread -> no intra-stage hazard; one barrier per double-stage)
    #pragma unroll
    for (int s = 8; s >= 0; s -= 2) {
        const int q = 1 << s;
        const int j = tid & (q - 1);
        const int i0 = ((tid >> s) << (s + 2)) | j;
        const float2 u  = twl[P(j << (8 - s))];   // W^{j*256/q}
        const float2 w2 = twl[P(j << (9 - s))];   // W^{j*512/q}
        #pragma unroll
        for (int a = 0; a < 2; ++a) {
            float2 a0 = z[a][P(i0)];
            float2 a1 = z[a][P(i0 + q)];
            float2 a2 = z[a][P(i0 + 2 * q)];
            float2 a3 = z[a][P(i0 + 3 * q)];
            float b0r = a0.x + a2.x, b0i = a0.y + a2.y;
            float b1r = a1.x + a3.x, b1i = a1.y + a3.y;
            float t2r = a0.x - a2.x, t2i = a0.y - a2.y;
            float t3r = a1.x - a3.x, t3i = a1.y - a3.y;
            float b2r = t2r * u.x - t2i * u.y, b2i = t2r * u.y + t2i * u.x;
            float m3r = t3r * u.x - t3i * u.y, m3i = t3r * u.y + t3i * u.x;
            float b3r = m3i, b3i = -m3r;    // *(W^256) = *(-i)
            float2 c0 = make_float2(b0r + b1r, b0i + b1i);
            float d1r = b0r - b1r, d1i = b0i - b1i;
            float2 c1 = make_float2(d1r * w2.x - d1i * w2.y, d1r * w2.y + d1i * w2.x);
            float2 c2 = make_float2(b2r + b3r, b2i + b3i);
            float d3r = b2r - b3r, d3i = b2i - b3i;
            float2 c3 = make_float2(d3r * w2.x - d3i * w2.y, d3r * w2.y + d3i * w2.x);
            z[a][P(i0)]         = c0;
            z[a][P(i0 + q)]     = c1;
            z[a][P(i0 + 2 * q)] = c2;
            z[a][P(i0 + 3 * q)] = c3;
        }
        __syncthreads();
    }

    // outputs bit-reversed: Z[k] sits at z[a][brev10(k)]
    const int k = tid;
    const int nk = (1024 - k) & 1023;
    const int rk = (int)(__brev((unsigned)k) >> 22);
    const int rn = (int)(__brev((unsigned)nk) >> 22);
    #pragma unroll
    for (int a = 0; a < 2; ++a) {
        const int fa = f0 + 2 * a;
        float2 zk = z[a][P(rk)], zn = z[a][P(rn)];
        float x0r = 0.5f * (zk.x + zn.x), x0i = 0.5f * (zk.y - zn.y);
        float x1r = 0.5f * (zk.y + zn.y), x1i = 0.5f * (zn.x - zk.x);
        float* yrow = Y + ((size_t)b * NBINS + k) * TT;
        yrow[fa] = x0r * x0r + x0i * x0i;
        if (fa + 1 < TT) yrow[fa + 1] = x1r * x1r + x1i * x1i;
    }
}

// ---------------------------------------------------------------- per-subband
// ONE ROW PER WAVE (2048 blocks x 4 waves). dec flags in ballot registers,
// wave-local compaction, private per-row output region, NO atomics.
__global__ __launch_bounds__(256) void subband_kernel(
        const float* __restrict__ Y, unsigned* __restrict__ compact,
        int* __restrict__ rowcnt) {
    __shared__ float ys[4][272];

    const int tid = threadIdx.x;
    const int lane = tid & 63;
    const int wave = tid >> 6;
    const int row = blockIdx.x * 4 + wave;
    const float* src = Y + (size_t)row * TT;

    float v[5];
    #pragma unroll
    for (int c = 0; c < 5; ++c) {
        int t = c * 64 + lane;
        v[c] = (t < TT) ? src[t] : 0.0f;
        if (t < TT) ys[wave][t] = v[c];
    }
    __syncthreads();                 // the only barrier

    const float* yy = ys[wave];

    unsigned long long m[5];
    #pragma unroll
    for (int c = 0; c < 5; ++c) {
        int t = c * 64 + lane;
        bool d = (t < TT - 1) && (yy[t + 1] < v[c]);
        m[c] = __ballot(d);
    }

    auto runl = [&](int c, int l) -> int {
        unsigned long long lo = m[c] >> l;
        if (l && c < 4) lo |= m[c + 1] << (64 - l);
        unsigned win = (unsigned)lo & 0xFFFu;
        return (win == 0xFFFu) ? 12 : (__ffs((int)~win) - 1);
    };

    int rl[5];
    int mx = 0;
    #pragma unroll
    for (int c = 0; c < 5; ++c) { rl[c] = runl(c, lane); mx = max(mx, rl[c]); }
    #pragma unroll
    for (int o = 32; o; o >>= 1) mx = max(mx, __shfl_xor(mx, o));
    const int maxrun = mx;           // capped at 12, uniform across wave

    if (maxrun < 2) {                // has_any == false
        if (lane == 0) rowcnt[row] = 0;
        return;
    }
    const int L = maxrun + 1;        // == min(13, true_maxrun+1)

    float sumx = 0.0f;
    #pragma unroll
    for (int j = 0; j < LMAX; ++j) if (j < L) sumx += (float)j;
    const float xm = sumx / (float)L;
    float den = 0.0f;
    #pragma unroll
    for (int j = 0; j < LMAX; ++j) if (j < L) { float xc = (float)j - xm; den += xc * xc; }

    unsigned keys[5];
    unsigned long long vm[5];
    #pragma unroll
    for (int c = 0; c < 5; ++c) {
        const int t = c * 64 + lane;
        bool sel = false;
        unsigned key = 0u;
        if (rl[c] >= L - 1) {        // start_mask (t+L<=T implied by run len)
            float edc[LMAX];
            float s = 0.0f;
            #pragma unroll
            for (int j = LMAX - 1; j >= 0; --j) {
                if (j < L) s += yy[t + j];
                edc[j] = s;
            }
            float db0 = 10.0f * log10f(fmaxf(edc[0], 1e-10f));
            float scl[LMAX];
            float s1 = 0.0f;
            float last = 0.0f;
            #pragma unroll
            for (int j = 0; j < LMAX; ++j) {
                if (j < L) {
                    float db = 10.0f * log10f(fmaxf(edc[j], 1e-10f));
                    float sc = db - db0;
                    scl[j] = sc;
                    s1 += sc;
                    if (j == L - 1) last = sc;
                }
            }
            if (last < -10.0f) {     // selected
                const float ym = s1 / (float)L;
                float num = 0.0f;
                #pragma unroll
                for (int j = 0; j < LMAX; ++j)
                    if (j < L) num += ((float)j - xm) * (scl[j] - ym);
                const float slope = num / den;
                float rt60 = (-60.0f / slope) * 0.0375f;   // * HOP/FS
                sel = true;
                key = f2key(rt60);
            }
        }
        vm[c] = __ballot(sel);       // uniform point
        keys[c] = key;
    }

    unsigned* dst = compact + (size_t)row * TT;
    const unsigned long long below = (1ull << lane) - 1ull;
    int base = 0;
    #pragma unroll
    for (int c = 0; c < 5; ++c) {
        if (vm[c] & (1ull << lane))
            dst[base + (int)__popcll(vm[c] & below)] = keys[c];
        base += (int)__popcll(vm[c]);
    }
    if (lane == 0) rowcnt[row] = base;
}

// ---------------------------------------------------------------- median
// one block per batch: exact k-th smallest via 3-pass (14+14+4 bit) LDS radix
// select. Conflict-free chunk sums (rotated index), shfl-based parallel rank
// selection (no serial tid0 scans).
__global__ __launch_bounds__(256) void median_kernel(
        const unsigned* __restrict__ compact, const int* __restrict__ rowcnt,
        const float* __restrict__ coeffs, float* __restrict__ out) {
    __shared__ unsigned hist[16384];
    __shared__ unsigned wsum[4];
    __shared__ int sh_sel;
    __shared__ unsigned sh_kkc;
    __shared__ unsigned sh_kk, sh_prefix, sh_pmask;
    __shared__ int sh_n;

    const int b = blockIdx.x;
    const int tid = threadIdx.x;
    const int lane = tid & 63;
    const int wave = tid >> 6;
    const int myrow = b * NBINS + tid;
    const int myc = rowcnt[myrow];
    const unsigned* mykeys = compact + (size_t)myrow * TT;

    // total n = sum of 256 row counts (wave shfl-scan + 4-way combine)
    {
        unsigned x = (unsigned)myc;
        #pragma unroll
        for (int o = 1; o < 64; o <<= 1) { unsigned t = __shfl_up(x, o); if (lane >= o) x += t; }
        if (lane == 63) wsum[wave] = x;
        __syncthreads();
        if (tid == 0) {
            int n = (int)(wsum[0] + wsum[1] + wsum[2] + wsum[3]);
            sh_n = n;
            sh_kk = (n > 0) ? (unsigned)((n - 1) / 2) : 0u;
            sh_prefix = 0u; sh_pmask = 0u;
        }
        __syncthreads();
    }
    const int n = sh_n;
    if (n == 0) {
        if (tid == 0) out[b] = 0.5f;     // DEFAULT_RT60 (> 0.01 clamp)
        return;
    }

    const int shifts[3] = {18, 4, 0};
    for (int p = 0; p < 3; ++p) {
        const int shift = shifts[p];
        const bool big = (p < 2);

        if (big) {
            uint4* h4 = (uint4*)hist;
            for (int i = tid; i < 4096; i += 256) h4[i] = make_uint4(0u, 0u, 0u, 0u);
        } else if (tid < 16) hist[tid] = 0u;
        __syncthreads();

        const unsigned pfx = sh_prefix, pm = sh_pmask;
        const unsigned bmask = big ? 16383u : 15u;
        for (int i = 0; i < myc; ++i) {
            unsigned k = mykeys[i];
            if ((k & pm) == pfx) atomicAdd(&hist[(k >> shift) & bmask], 1u);
        }
        __syncthreads();

        const unsigned kk = sh_kk;
        if (big) {
            // per-thread 64-bin chunk sum, rotated index -> conflict-free
            unsigned s = 0;
            const int base = tid * 64;
            #pragma unroll 8
            for (int ii = 0; ii < 64; ++ii) s += hist[base + ((ii + tid) & 63)];
            // block inclusive scan of the 256 chunk sums
            unsigned x = s;
            #pragma unroll
            for (int o = 1; o < 64; o <<= 1) { unsigned t = __shfl_up(x, o); if (lane >= o) x += t; }
            if (lane == 63) wsum[wave] = x;
            __syncthreads();
            unsigned woff = 0;
            for (int w = 0; w < wave; ++w) woff += wsum[w];
            const unsigned incl = x + woff, excl = incl - s;
            if (kk >= excl && kk < incl) { sh_sel = tid; sh_kkc = kk - excl; }
            __syncthreads();
            const int sel = sh_sel;
            const unsigned kkc = sh_kkc;
            if (wave == 0) {                 // rank-select within the 64-bin chunk
                unsigned h = hist[sel * 64 + lane];
                unsigned xx = h;
                #pragma unroll
                for (int o = 1; o < 64; o <<= 1) { unsigned t = __shfl_up(xx, o); if (lane >= o) xx += t; }
                unsigned ex = xx - h;
                if (kkc >= ex && kkc < xx) {
                    sh_prefix = pfx | ((unsigned)(sel * 64 + lane) << shift);
                    sh_pmask  = pm | (16383u << shift);
                    sh_kk = kkc - ex;
                }
            }
            __syncthreads();
        } else {
            if (wave == 0) {
                unsigned h = (lane < 16) ? hist[lane] : 0u;
                unsigned xx = h;
                #pragma unroll
                for (int o = 1; o < 64; o <<= 1) { unsigned t = __shfl_up(xx, o); if (lane >= o) xx += t; }
                unsigned ex = xx - h;
                if (lane < 16 && kk >= ex && kk < xx)
                    sh_prefix = pfx | (unsigned)lane;   // shift == 0
            }
            __syncthreads();
        }
    }

    if (tid == 0) {
        unsigned kx = sh_prefix;
        unsigned fb = (kx & 0x80000000u) ? (kx & 0x7FFFFFFFu) : ~kx;
        float med = __uint_as_float(fb);
        out[b] = fmaxf(coeffs[0] + coeffs[1] * med, 0.01f);
    }
}

// ----------------------------------------------------------------
extern "C" void kernel_launch(void* const* d_in, const int* in_sizes, int n_in,
                              void* d_out, int out_size, void* d_ws, size_t ws_size,
                              hipStream_t stream) {
    const float* y = (const float*)d_in[0];
    const float* coeffs = (const float*)d_in[1];
    float* out = (float*)d_out;

    const size_t YB = (size_t)NROWS * TT * sizeof(float);
    char* base = (char*)d_ws;
    float* Y = (float*)base;
    unsigned* compact = (unsigned*)(base + YB);
    int* rowcnt = (int*)(base + 2 * YB);
    float2* tw = (float2*)(base + 2 * YB + (size_t)NROWS * sizeof(int));
    float* wtab = (float*)((char*)tw + 512 * sizeof(float2));

    init_kernel<<<4, 256, 0, stream>>>(tw, wtab);
    stft_power_kernel<<<dim3((TT + 3) / 4, NB), 256, 0, stream>>>(y, tw, wtab, Y);
    subband_kernel<<<NROWS / 4, 256, 0, stream>>>(Y, compact, rowcnt);
    median_kernel<<<NB, 256, 0, stream>>>(compact, rowcnt, coeffs, out);
}

// Round 8
// 108.042 us; speedup vs baseline: 3.0605x; 1.0668x over previous
//
#include <hip/hip_runtime.h>
#include <hip/hip_bf16.h>
#include <math.h>

#define NB 32          // batch
#define TLEN 160000    // samples per batch
#define HOP 600
#define NBINS 256
#define TT 267         // frames: 1 + (160000+1024-1024)/600
#define TTP 268        // padded row stride (even -> aligned float2 stores)
#define NROWS (NB * NBINS)  // 8192
#define LMAX 13

__device__ __forceinline__ unsigned f2key(float f) {
    unsigned b = __float_as_uint(f);
    return (b & 0x80000000u) ? ~b : (b | 0x80000000u);
}
// twiddle LDS padding
__device__ __forceinline__ int P(int i) { return i + (i >> 4); }
// data LDS XOR swizzle: flips bits 2-5 by bits 6-9 -> conflict-free for
// stride-64 sets, stride-4 sets, and quad-contiguous b128 access
__device__ __forceinline__ int Q(int i) { return i ^ ((i >> 4) & 0x3C); }
__device__ __forceinline__ float2 cmul(float2 a, float2 w) {
    return make_float2(a.x * w.x - a.y * w.y, a.x * w.y + a.y * w.x);
}
__device__ __forceinline__ float2 cadd(float2 a, float2 b) { return make_float2(a.x + b.x, a.y + b.y); }
__device__ __forceinline__ float2 csub(float2 a, float2 b) { return make_float2(a.x - b.x, a.y - b.y); }

// ---------------------------------------------------------------- init: twiddles + window
__global__ void init_kernel(float2* __restrict__ tw, float* __restrict__ wtab) {
    int j = blockIdx.x * blockDim.x + threadIdx.x;
    if (j < 512) {
        double ang = -2.0 * 3.14159265358979323846 * (double)j / 1024.0;
        tw[j] = make_float2((float)cos(ang), (float)sin(ang));
    }
    if (j < 800) {
        float arg = (6.2831855f * (float)j) / 800.0f;
        wtab[j] = 0.5f - 0.5f * cosf(arg);
    }
}

// ---------------------------------------------------------------- STFT power
// one block per (8 frames, batch) = 4 complex 1024-pt DIF FFTs (each packs two
// real frames). Radix-16/16/4 decomposition: 3 LDS round-trips, 4 barriers.
// Each lane holds 16 complex elements in registers per round.
__global__ __launch_bounds__(256) void stft_power_kernel(
        const float* __restrict__ y, const float2* __restrict__ twg,
        const float* __restrict__ wtab, float* __restrict__ Y) {
    __shared__ float2 zz[4][1024];
    __shared__ float2 twl[544];

    const int g = blockIdx.x;
    const int b = blockIdx.y;
    const int tid = threadIdx.x;
    const int f0 = 8 * g;

    for (int j = tid; j < 512; j += 256) twl[P(j)] = twg[j];

    // ---- stage in: window + pack two real frames per FFT (coalesced float4)
    const float* yb = y + (size_t)b * TLEN;
    #pragma unroll
    for (int a = 0; a < 4; ++a) {
        const int fa = f0 + 2 * a;
        if (fa >= TT) break;
        const bool hasB = (fa + 1 < TT);
        const int base = fa * HOP - 512;        // reflect pad K/2 = 512
        const int i = 4 * tid;
        float2 q4[4];
        if (base >= 0 && hasB) {                // fast path: no reflection possible
            if (i >= 112 && i < 912) {          // centered 800-tap hann
                float4 w4 = *(const float4*)(wtab + (i - 112));
                float4 a0 = *(const float4*)(yb + base + i);
                float4 a1 = *(const float4*)(yb + base + HOP + i);
                q4[0] = make_float2(a0.x * w4.x, a1.x * w4.x);
                q4[1] = make_float2(a0.y * w4.y, a1.y * w4.y);
                q4[2] = make_float2(a0.z * w4.z, a1.z * w4.z);
                q4[3] = make_float2(a0.w * w4.w, a1.w * w4.w);
            } else {
                q4[0] = q4[1] = q4[2] = q4[3] = make_float2(0.f, 0.f);
            }
        } else {                                // fa==0 (left reflect) or fa==266 (no 2nd frame)
            #pragma unroll
            for (int m = 0; m < 4; ++m) {
                const int ii = i + m;
                float v0 = 0.f, v1 = 0.f;
                if (ii >= 112 && ii < 912) {
                    float w = wtab[ii - 112];
                    int p0 = base + ii;
                    int q0 = p0 < 0 ? -p0 : p0; // right edge never reflects (max 159999)
                    v0 = yb[q0] * w;
                    if (hasB) v1 = yb[p0 + HOP] * w;   // >= 200, in bounds
                }
                q4[m] = make_float2(v0, v1);
            }
        }
        float4* dst = (float4*)&zz[a][Q(i)];    // Q preserves quad contiguity
        dst[0] = make_float4(q4[0].x, q4[0].y, q4[1].x, q4[1].y);
        dst[1] = make_float4(q4[2].x, q4[2].y, q4[3].x, q4[3].y);
    }
    __syncthreads();

    // ---- round 1: DIF layers H=512,256,128,64 on {j + 64k} in registers
    {
        const int a = tid >> 6, j = tid & 63;
        float2 x[16];
        #pragma unroll
        for (int k = 0; k < 16; ++k) x[k] = zz[a][Q(j + 64 * k)];
        #pragma unroll
        for (int k = 0; k < 8; ++k) {           // H=512: e=(idx mod 512)*1
            float2 s = csub(x[k], x[k + 8]);
            x[k] = cadd(x[k], x[k + 8]);
            x[k + 8] = cmul(s, twl[P(j + 64 * k)]);
        }
        #pragma unroll
        for (int h = 0; h < 16; h += 8)         // H=256: e=(idx mod 256)*2
            #pragma unroll
            for (int k = 0; k < 4; ++k) {
                float2 s = csub(x[h + k], x[h + k + 4]);
                x[h + k] = cadd(x[h + k], x[h + k + 4]);
                x[h + k + 4] = cmul(s, twl[P(2 * j + 128 * k)]);
            }
        #pragma unroll
        for (int h = 0; h < 16; h += 4)         // H=128: e=(idx mod 128)*4
            #pragma unroll
            for (int k = 0; k < 2; ++k) {
                float2 s = csub(x[h + k], x[h + k + 2]);
                x[h + k] = cadd(x[h + k], x[h + k + 2]);
                x[h + k + 2] = cmul(s, twl[P(4 * j + 256 * k)]);
            }
        {
            const float2 wD = twl[P(8 * j)];    // H=64: e=(idx mod 64)*8
            #pragma unroll
            for (int h = 0; h < 16; h += 2) {
                float2 s = csub(x[h], x[h + 1]);
                x[h] = cadd(x[h], x[h + 1]);
                x[h + 1] = cmul(s, wD);
            }
        }
        #pragma unroll
        for (int k = 0; k < 16; ++k) zz[a][Q(j + 64 * k)] = x[k];
    }
    __syncthreads();

    // ---- round 2: DIF layers H=32,16,8,4 on {64g + j2 + 4k} in registers
    {
        const int a = tid >> 6, l = tid & 63;
        const int gg = l >> 2, j2 = l & 3;
        const int b0 = 64 * gg + j2;
        float2 x[16];
        #pragma unroll
        for (int k = 0; k < 16; ++k) x[k] = zz[a][Q(b0 + 4 * k)];
        #pragma unroll
        for (int k = 0; k < 8; ++k) {           // H=32: e=(idx mod 32)*16
            float2 s = csub(x[k], x[k + 8]);
            x[k] = cadd(x[k], x[k + 8]);
            x[k + 8] = cmul(s, twl[P(16 * j2 + 64 * k)]);
        }
        #pragma unroll
        for (int h = 0; h < 16; h += 8)         // H=16: e=(idx mod 16)*32
            #pragma unroll
            for (int k = 0; k < 4; ++k) {
                float2 s = csub(x[h + k], x[h + k + 4]);
                x[h + k] = cadd(x[h + k], x[h + k + 4]);
                x[h + k + 4] = cmul(s, twl[P(32 * j2 + 128 * k)]);
            }
        #pragma unroll
        for (int h = 0; h < 16; h += 4)         // H=8: e=(idx mod 8)*64
            #pragma unroll
            for (int k = 0; k < 2; ++k) {
                float2 s = csub(x[h + k], x[h + k + 2]);
                x[h + k] = cadd(x[h + k], x[h + k + 2]);
                x[h + k + 2] = cmul(s, twl[P(64 * (j2 + 4 * k))]);
            }
        {
            const float2 wD = twl[P(128 * j2)]; // H=4: e=(idx mod 4)*128
            #pragma unroll
            for (int h = 0; h < 16; h += 2) {
                float2 s = csub(x[h], x[h + 1]);
                x[h] = cadd(x[h], x[h + 1]);
                x[h + 1] = cmul(s, wD);
            }
        }
        #pragma unroll
        for (int k = 0; k < 16; ++k) zz[a][Q(b0 + 4 * k)] = x[k];
    }
    __syncthreads();

    // ---- round 3: twiddle-free radix-4 on quads (b128 via Q contiguity)
    #pragma unroll
    for (int a = 0; a < 4; ++a) {
        float4* pp = (float4*)&zz[a][Q(4 * tid)];
        float4 r0 = pp[0], r1 = pp[1];
        float2 x0 = make_float2(r0.x, r0.y), x1 = make_float2(r0.z, r0.w);
        float2 x2 = make_float2(r1.x, r1.y), x3 = make_float2(r1.z, r1.w);
        float2 e0 = cadd(x0, x2);               // H=2 pair (0,2), W^0
        float2 e1 = cadd(x1, x3);               // H=2 pair (1,3) top
        float2 d0 = csub(x0, x2);
        float2 d1 = csub(x1, x3);
        float2 d1m = make_float2(d1.y, -d1.x);  // * W^256 = -i
        pp[0] = make_float4(e0.x + e1.x, e0.y + e1.y, e0.x - e1.x, e0.y - e1.y);
        pp[1] = make_float4(d0.x + d1m.x, d0.y + d1m.y, d0.x - d1m.x, d0.y - d1m.y);
    }
    __syncthreads();

    // ---- unpack two real spectra per FFT; Z[k] sits at brev10(k)
    const int k = tid;
    const int nk = (1024 - k) & 1023;
    const int rk = (int)(__brev((unsigned)k) >> 22);
    const int rn = (int)(__brev((unsigned)nk) >> 22);
    float* yrow = Y + ((size_t)b * NBINS + k) * TTP;
    #pragma unroll
    for (int a = 0; a < 4; ++a) {
        const int fa = f0 + 2 * a;
        if (fa >= TT) break;
        float2 zk = zz[a][Q(rk)], zn = zz[a][Q(rn)];
        float x0r = 0.5f * (zk.x + zn.x), x0i = 0.5f * (zk.y - zn.y);
        float x1r = 0.5f * (zk.y + zn.y), x1i = 0.5f * (zn.x - zk.x);
        *(float2*)(yrow + fa) =
            make_float2(x0r * x0r + x0i * x0i, x1r * x1r + x1i * x1i);
    }
}

// ---------------------------------------------------------------- per-subband
// ONE ROW PER WAVE (2048 blocks x 4 waves). dec flags in ballot registers,
// wave-local compaction, private per-row output region, NO atomics.
__global__ __launch_bounds__(256) void subband_kernel(
        const float* __restrict__ Y, unsigned* __restrict__ compact,
        int* __restrict__ rowcnt) {
    __shared__ float ys[4][272];

    const int tid = threadIdx.x;
    const int lane = tid & 63;
    const int wave = tid >> 6;
    const int row = blockIdx.x * 4 + wave;
    const float* src = Y + (size_t)row * TTP;

    float v[5];
    #pragma unroll
    for (int c = 0; c < 5; ++c) {
        int t = c * 64 + lane;
        v[c] = (t < TT) ? src[t] : 0.0f;
        if (t < TT) ys[wave][t] = v[c];
    }
    __syncthreads();                 // the only barrier

    const float* yy = ys[wave];

    unsigned long long m[5];
    #pragma unroll
    for (int c = 0; c < 5; ++c) {
        int t = c * 64 + lane;
        bool d = (t < TT - 1) && (yy[t + 1] < v[c]);
        m[c] = __ballot(d);
    }

    auto runl = [&](int c, int l) -> int {
        unsigned long long lo = m[c] >> l;
        if (l && c < 4) lo |= m[c + 1] << (64 - l);
        unsigned win = (unsigned)lo & 0xFFFu;
        return (win == 0xFFFu) ? 12 : (__ffs((int)~win) - 1);
    };

    int rl[5];
    int mx = 0;
    #pragma unroll
    for (int c = 0; c < 5; ++c) { rl[c] = runl(c, lane); mx = max(mx, rl[c]); }
    #pragma unroll
    for (int o = 32; o; o >>= 1) mx = max(mx, __shfl_xor(mx, o));
    const int maxrun = mx;           // capped at 12, uniform across wave

    if (maxrun < 2) {                // has_any == false
        if (lane == 0) rowcnt[row] = 0;
        return;
    }
    const int L = maxrun + 1;        // == min(13, true_maxrun+1)

    float sumx = 0.0f;
    #pragma unroll
    for (int j = 0; j < LMAX; ++j) if (j < L) sumx += (float)j;
    const float xm = sumx / (float)L;
    float den = 0.0f;
    #pragma unroll
    for (int j = 0; j < LMAX; ++j) if (j < L) { float xc = (float)j - xm; den += xc * xc; }

    unsigned keys[5];
    unsigned long long vm[5];
    #pragma unroll
    for (int c = 0; c < 5; ++c) {
        const int t = c * 64 + lane;
        bool sel = false;
        unsigned key = 0u;
        if (rl[c] >= L - 1) {        // start_mask (t+L<=T implied by run len)
            float edc[LMAX];
            float s = 0.0f;
            #pragma unroll
            for (int j = LMAX - 1; j >= 0; --j) {
                if (j < L) s += yy[t + j];
                edc[j] = s;
            }
            float db0 = 10.0f * log10f(fmaxf(edc[0], 1e-10f));
            float scl[LMAX];
            float s1 = 0.0f;
            float last = 0.0f;
            #pragma unroll
            for (int j = 0; j < LMAX; ++j) {
                if (j < L) {
                    float db = 10.0f * log10f(fmaxf(edc[j], 1e-10f));
                    float sc = db - db0;
                    scl[j] = sc;
                    s1 += sc;
                    if (j == L - 1) last = sc;
                }
            }
            if (last < -10.0f) {     // selected
                const float ym = s1 / (float)L;
                float num = 0.0f;
                #pragma unroll
                for (int j = 0; j < LMAX; ++j)
                    if (j < L) num += ((float)j - xm) * (scl[j] - ym);
                const float slope = num / den;
                float rt60 = (-60.0f / slope) * 0.0375f;   // * HOP/FS
                sel = true;
                key = f2key(rt60);
            }
        }
        vm[c] = __ballot(sel);       // uniform point
        keys[c] = key;
    }

    unsigned* dst = compact + (size_t)row * TTP;
    const unsigned long long below = (1ull << lane) - 1ull;
    int base = 0;
    #pragma unroll
    for (int c = 0; c < 5; ++c) {
        if (vm[c] & (1ull << lane))
            dst[base + (int)__popcll(vm[c] & below)] = keys[c];
        base += (int)__popcll(vm[c]);
    }
    if (lane == 0) rowcnt[row] = base;
}

// ---------------------------------------------------------------- median
// one block per batch: exact k-th smallest via 3-pass (14+14+4 bit) LDS radix
// select. Conflict-free chunk sums (rotated index), shfl-based parallel rank
// selection (no serial tid0 scans).
__global__ __launch_bounds__(256) void median_kernel(
        const unsigned* __restrict__ compact, const int* __restrict__ rowcnt,
        const float* __restrict__ coeffs, float* __restrict__ out) {
    __shared__ unsigned hist[16384];
    __shared__ unsigned wsum[4];
    __shared__ int sh_sel;
    __shared__ unsigned sh_kkc;
    __shared__ unsigned sh_kk, sh_prefix, sh_pmask;
    __shared__ int sh_n;

    const int b = blockIdx.x;
    const int tid = threadIdx.x;
    const int lane = tid & 63;
    const int wave = tid >> 6;
    const int myrow = b * NBINS + tid;
    const int myc = rowcnt[myrow];
    const unsigned* mykeys = compact + (size_t)myrow * TTP;

    {
        unsigned x = (unsigned)myc;
        #pragma unroll
        for (int o = 1; o < 64; o <<= 1) { unsigned t = __shfl_up(x, o); if (lane >= o) x += t; }
        if (lane == 63) wsum[wave] = x;
        __syncthreads();
        if (tid == 0) {
            int n = (int)(wsum[0] + wsum[1] + wsum[2] + wsum[3]);
            sh_n = n;
            sh_kk = (n > 0) ? (unsigned)((n - 1) / 2) : 0u;
            sh_prefix = 0u; sh_pmask = 0u;
        }
        __syncthreads();
    }
    const int n = sh_n;
    if (n == 0) {
        if (tid == 0) out[b] = 0.5f;     // DEFAULT_RT60 (> 0.01 clamp)
        return;
    }

    const int shifts[3] = {18, 4, 0};
    for (int p = 0; p < 3; ++p) {
        const int shift = shifts[p];
        const bool big = (p < 2);

        if (big) {
            uint4* h4 = (uint4*)hist;
            for (int i = tid; i < 4096; i += 256) h4[i] = make_uint4(0u, 0u, 0u, 0u);
        } else if (tid < 16) hist[tid] = 0u;
        __syncthreads();

        const unsigned pfx = sh_prefix, pm = sh_pmask;
        const unsigned bmask = big ? 16383u : 15u;
        for (int i = 0; i < myc; ++i) {
            unsigned k = mykeys[i];
            if ((k & pm) == pfx) atomicAdd(&hist[(k >> shift) & bmask], 1u);
        }
        __syncthreads();

        const unsigned kk = sh_kk;
        if (big) {
            unsigned s = 0;
            const int base = tid * 64;
            #pragma unroll 8
            for (int ii = 0; ii < 64; ++ii) s += hist[base + ((ii + tid) & 63)];
            unsigned x = s;
            #pragma unroll
            for (int o = 1; o < 64; o <<= 1) { unsigned t = __shfl_up(x, o); if (lane >= o) x += t; }
            if (lane == 63) wsum[wave] = x;
            __syncthreads();
            unsigned woff = 0;
            for (int w = 0; w < wave; ++w) woff += wsum[w];
            const unsigned incl = x + woff, excl = incl - s;
            if (kk >= excl && kk < incl) { sh_sel = tid; sh_kkc = kk - excl; }
            __syncthreads();
            const int sel = sh_sel;
            const unsigned kkc = sh_kkc;
            if (wave == 0) {
                unsigned h = hist[sel * 64 + lane];
                unsigned xx = h;
                #pragma unroll
                for (int o = 1; o < 64; o <<= 1) { unsigned t = __shfl_up(xx, o); if (lane >= o) xx += t; }
                unsigned ex = xx - h;
                if (kkc >= ex && kkc < xx) {
                    sh_prefix = pfx | ((unsigned)(sel * 64 + lane) << shift);
                    sh_pmask  = pm | (16383u << shift);
                    sh_kk = kkc - ex;
                }
            }
            __syncthreads();
        } else {
            if (wave == 0) {
                unsigned h = (lane < 16) ? hist[lane] : 0u;
                unsigned xx = h;
                #pragma unroll
                for (int o = 1; o < 64; o <<= 1) { unsigned t = __shfl_up(xx, o); if (lane >= o) xx += t; }
                unsigned ex = xx - h;
                if (lane < 16 && kk >= ex && kk < xx)
                    sh_prefix = pfx | (unsigned)lane;   // shift == 0
            }
            __syncthreads();
        }
    }

    if (tid == 0) {
        unsigned kx = sh_prefix;
        unsigned fb = (kx & 0x80000000u) ? (kx & 0x7FFFFFFFu) : ~kx;
        float med = __uint_as_float(fb);
        out[b] = fmaxf(coeffs[0] + coeffs[1] * med, 0.01f);
    }
}

// ----------------------------------------------------------------
extern "C" void kernel_launch(void* const* d_in, const int* in_sizes, int n_in,
                              void* d_out, int out_size, void* d_ws, size_t ws_size,
                              hipStream_t stream) {
    const float* y = (const float*)d_in[0];
    const float* coeffs = (const float*)d_in[1];
    float* out = (float*)d_out;

    // ws layout:
    //   [0]        Y       : NROWS*TTP floats = 8,781,824 B (stride-268 rows)
    //   [YB]       compact : NROWS*TTP uints (per-row private regions)
    //   [2*YB]     rowcnt  : NROWS ints (fully overwritten per call)
    //   [..]       tw      : 512 float2 ; wtab : 800 floats
    const size_t YB = (size_t)NROWS * TTP * sizeof(float);
    char* base = (char*)d_ws;
    float* Y = (float*)base;
    unsigned* compact = (unsigned*)(base + YB);
    int* rowcnt = (int*)(base + 2 * YB);
    float2* tw = (float2*)(base + 2 * YB + (size_t)NROWS * sizeof(int));
    float* wtab = (float*)((char*)tw + 512 * sizeof(float2));

    init_kernel<<<4, 256, 0, stream>>>(tw, wtab);
    stft_power_kernel<<<dim3((TT + 7) / 8, NB), 256, 0, stream>>>(y, tw, wtab, Y);
    subband_kernel<<<NROWS / 4, 256, 0, stream>>>(Y, compact, rowcnt);
    median_kernel<<<NB, 256, 0, stream>>>(compact, rowcnt, coeffs, out);
}